// Round 2
// baseline (79.238 us; speedup 1.0000x reference)
//
#include <hip/hip_runtime.h>
#include <stdint.h>

typedef float    f32x4  __attribute__((ext_vector_type(4)));
typedef __bf16   bf16x8 __attribute__((ext_vector_type(8)));
typedef uint32_t u32x4  __attribute__((ext_vector_type(4)));
typedef unsigned short u16x4 __attribute__((ext_vector_type(4)));

#define AS1 __attribute__((address_space(1)))
#define AS3 __attribute__((address_space(3)))

__device__ __forceinline__ unsigned short f2bf_bits(float f) {
  uint32_t u = __builtin_bit_cast(uint32_t, f);
  u += 0x7fffu + ((u >> 16) & 1u);      // RNE to bf16
  return (unsigned short)(u >> 16);
}

// ---------------- kernel 0: At[col][k] (bf16) = A[k][col] ----------------
// A: [256][1024] f32  ->  At: [1024][256] bf16 (in d_ws)
__global__ void k_transpose_cvt(const float* __restrict__ A,
                                unsigned short* __restrict__ At) {
  int n = blockIdx.x * blockDim.x + threadIdx.x;  // 65536 threads
  int o = n << 2;                                 // 4 elements per thread
  int col = o >> 8;
  int k   = o & 255;
  u16x4 v;
#pragma unroll
  for (int j = 0; j < 4; ++j) v[j] = f2bf_bits(A[(size_t)(k + j) * 1024 + col]);
  *reinterpret_cast<u16x4*>(At + o) = v;          // coalesced write
}

// ---------------- kernel 1: fused GEMM + silu rowsum + zero-fill + diag ----
// x: [65536][256] f32, At: [1024][256] bf16, out: [1024][256][256] f32
// Block: 256 threads (4 waves), BM = 128 rows. Grid: 512 blocks.
// Wave w owns rows w*32..w*32+31 (2 row-groups of 16, MFMA 16x16x32 bf16).
// Per N-tile (16 cols of h=1024): stage 8KB of At into LDS (swizzled via
// pre-swizzled global source + linear global_load_lds dest), 16 MFMA/wave,
// silu+accumulate. Each thread also zero-fills 2 float4 of its block's
// exclusive 512KB out region per tile. Epilogue writes the 512 diagonals.
__launch_bounds__(256, 2)
__global__ void k_gemm_fused(const float* __restrict__ x,
                             const unsigned short* __restrict__ At,
                             float* __restrict__ out) {
  __shared__ alignas(16) char lds[8192];

  const int tid  = threadIdx.x;
  const int lane = tid & 63;
  const int w    = tid >> 6;          // wave 0..3
  const int bIdx = blockIdx.x;        // 0..511
  const int brow = bIdx * 128;

  const int col = lane & 15;          // A-frag row / B-frag col / C col
  const int hi  = lane >> 4;          // k-subblock select

  // ---- x fragments in registers: rows w*32 + rg*16 + col, k = s*32 + hi*8 ----
  bf16x8 xf[2][8];
#pragma unroll
  for (int rg = 0; rg < 2; ++rg) {
    const float* xr = x + (size_t)(brow + w * 32 + rg * 16 + col) * 256;
#pragma unroll
    for (int s = 0; s < 8; ++s) {
      f32x4 a = __builtin_nontemporal_load(
          reinterpret_cast<const f32x4*>(xr + s * 32 + hi * 8));
      f32x4 b = __builtin_nontemporal_load(
          reinterpret_cast<const f32x4*>(xr + s * 32 + hi * 8 + 4));
      bf16x8 f;
      f[0] = (__bf16)a[0]; f[1] = (__bf16)a[1];
      f[2] = (__bf16)a[2]; f[3] = (__bf16)a[3];
      f[4] = (__bf16)b[0]; f[5] = (__bf16)b[1];
      f[6] = (__bf16)b[2]; f[7] = (__bf16)b[3];
      xf[rg][s] = f;
    }
  }

  // staging: LDS linear chunk p (16B) <- global byte (p ^ swz(p)); swz is an
  // involution on bits 4..6 keyed by col bits (p>>9), so ds_read side applies
  // the same XOR and gets conflict-free b128 reads.
  uint32_t p0 = (uint32_t)(w * 2048 + lane * 16);
  uint32_t so0 = p0 ^ (((p0 >> 9) & 7u) << 4);
  uint32_t p1 = p0 + 1024u;
  uint32_t so1 = p1 ^ (((p1 >> 9) & 7u) << 4);
  char* ldsw0 = lds + w * 2048;          // wave-uniform dest (HW adds lane*16)
  char* ldsw1 = lds + w * 2048 + 1024;

  // B-frag read base: element (col, k= s*32 + hi*8) -> byte col*512+s*64+hi*16,
  // XOR (col&7)<<4.  Fields are disjoint bits, so addr(s) = rbase ^ (s<<6).
  uint32_t rbase = ((uint32_t)(col * 512 + hi * 16)) ^ ((uint32_t)(col & 7) << 4);

  float sums[2][4] = {{0.f, 0.f, 0.f, 0.f}, {0.f, 0.f, 0.f, 0.f}};
  float* outblk = out + (size_t)bIdx * 131072;   // block's exclusive 512KB
  const f32x4 z4 = {0.f, 0.f, 0.f, 0.f};

  for (int tile = 0; tile < 64; ++tile) {
    const char* tsrc = (const char*)At + (size_t)tile * 8192;
    __builtin_amdgcn_global_load_lds((const AS1 uint32_t*)(tsrc + so0),
                                     (AS3 uint32_t*)ldsw0, 16, 0, 0);
    __builtin_amdgcn_global_load_lds((const AS1 uint32_t*)(tsrc + so1),
                                     (AS3 uint32_t*)ldsw1, 16, 0, 0);

    // zero-fill 2 float4 of this block's out region (overlaps with compute)
    float* zp = outblk + tile * 2048 + (tid << 2);
    __builtin_nontemporal_store(z4, reinterpret_cast<f32x4*>(zp));
    __builtin_nontemporal_store(z4, reinterpret_cast<f32x4*>(zp + 1024));

    __syncthreads();   // drains vmcnt(0): LDS tile ready

    bf16x8 bfr[8];
#pragma unroll
    for (int s = 0; s < 8; ++s) {
      uint32_t addr = rbase ^ ((uint32_t)s << 6);
      bfr[s] = __builtin_bit_cast(
          bf16x8, *reinterpret_cast<const u32x4*>(lds + addr));
    }
    f32x4 acc[2] = {{0.f, 0.f, 0.f, 0.f}, {0.f, 0.f, 0.f, 0.f}};
#pragma unroll
    for (int s = 0; s < 8; ++s) {
      acc[0] = __builtin_amdgcn_mfma_f32_16x16x32_bf16(xf[0][s], bfr[s], acc[0], 0, 0, 0);
      acc[1] = __builtin_amdgcn_mfma_f32_16x16x32_bf16(xf[1][s], bfr[s], acc[1], 0, 0, 0);
    }
#pragma unroll
    for (int rg = 0; rg < 2; ++rg)
#pragma unroll
      for (int j = 0; j < 4; ++j) {
        float z = acc[rg][j];
        float sig = __builtin_amdgcn_rcpf(1.0f + __expf(-z));
        sums[rg][j] += z * sig;
      }
    __syncthreads();   // LDS consumed; next tile may overwrite
  }

  // ---- reduce over the 16 column-lanes (C layout: col = lane&15) ----
#pragma unroll
  for (int rg = 0; rg < 2; ++rg)
#pragma unroll
    for (int j = 0; j < 4; ++j) {
      float v = sums[rg][j];
      v += __shfl_xor(v, 1, 64);
      v += __shfl_xor(v, 2, 64);
      v += __shfl_xor(v, 4, 64);
      v += __shfl_xor(v, 8, 64);
      sums[rg][j] = v;
    }

  // zero stores of the last tile were drained by the loop's final barrier;
  // block owns groups 2*bIdx, 2*bIdx+1 exclusively -> no inter-block hazard.
  if (col == 0) {
#pragma unroll
    for (int rg = 0; rg < 2; ++rg)
#pragma unroll
      for (int j = 0; j < 4; ++j) {
        int rb_ = brow + w * 32 + rg * 16 + hi * 4 + j;  // global row (= g*64+c)
        int g = rb_ >> 6;
        int c = rb_ & 63;
        float s = sums[rg][j];
        float* og = out + (size_t)g * 65536;
        og[(2 * c) * 256 + 128 + 2 * c]     =  s;   // out[g, i, 128+i], i=2c
        og[(2 * c + 1) * 256 + 129 + 2 * c] =  s;   // i=2c+1
        og[(128 + 2 * c) * 256 + 2 * c]     = -s;   // out[g, 128+i, i]
        og[(129 + 2 * c) * 256 + 2 * c + 1] = -s;
      }
  }
}

extern "C" void kernel_launch(void* const* d_in, const int* in_sizes, int n_in,
                              void* d_out, int out_size, void* d_ws, size_t ws_size,
                              hipStream_t stream) {
  const float* x = (const float*)d_in[0];   // [65536, 256]
  const float* A = (const float*)d_in[1];   // [256, 1024]
  float* out = (float*)d_out;               // [1024, 256, 256]
  unsigned short* At = (unsigned short*)d_ws;  // 512 KB bf16 transposed weights

  k_transpose_cvt<<<256, 256, 0, stream>>>(A, At);
  k_gemm_fused<<<512, 256, 0, stream>>>(x, At, out);
}